// Round 1
// baseline (1161.852 us; speedup 1.0000x reference)
//
#include <hip/hip_runtime.h>

#define S_LEN 4096
#define D_MODEL 2048
#define FF_DIM 8192

typedef __attribute__((ext_vector_type(8))) short s16x8;
typedef __attribute__((ext_vector_type(4))) short s16x4;
typedef __attribute__((ext_vector_type(4))) float f32x4;

__device__ __forceinline__ short f2bf(float f) {
  union { float f; unsigned u; } c; c.f = f;
  unsigned r = (c.u + 0x7fffu + ((c.u >> 16) & 1u)) >> 16;
  return (short)r;
}
__device__ __forceinline__ float bf2f(short s) {
  union { unsigned u; float f; } c; c.u = ((unsigned)(unsigned short)s) << 16;
  return c.f;
}

#define GLDS16(g, l) __builtin_amdgcn_global_load_lds( \
    (const __attribute__((address_space(1))) unsigned*)(g), \
    (__attribute__((address_space(3))) unsigned*)(l), 16, 0, 0)

// ---------------- fp32 -> bf16 bulk convert (n multiple of 8) ----------------
__global__ void conv_f32_bf16(const float* __restrict__ in, short* __restrict__ out, long n) {
  long i = ((long)blockIdx.x * blockDim.x + threadIdx.x) * 8;
  if (i >= n) return;
  f32x4 a = *(const f32x4*)(in + i);
  f32x4 b = *(const f32x4*)(in + i + 4);
  s16x8 o;
  o[0] = f2bf(a[0]); o[1] = f2bf(a[1]); o[2] = f2bf(a[2]); o[3] = f2bf(a[3]);
  o[4] = f2bf(b[0]); o[5] = f2bf(b[1]); o[6] = f2bf(b[2]); o[7] = f2bf(b[3]);
  *(s16x8*)(out + i) = o;
}

// ---------------- RMSNorm: fp32 [S,D=2048] -> bf16, block per row ----------------
__global__ void rmsnorm_kernel(const float* __restrict__ x, const float* __restrict__ w,
                               short* __restrict__ out) {
  const int row = blockIdx.x;
  const int t = threadIdx.x;
  const float* xr = x + (long)row * D_MODEL;
  f32x4 v0 = ((const f32x4*)xr)[t];
  f32x4 v1 = ((const f32x4*)xr)[256 + t];
  float ss = v0[0]*v0[0] + v0[1]*v0[1] + v0[2]*v0[2] + v0[3]*v0[3]
           + v1[0]*v1[0] + v1[1]*v1[1] + v1[2]*v1[2] + v1[3]*v1[3];
  #pragma unroll
  for (int o = 32; o > 0; o >>= 1) ss += __shfl_xor(ss, o, 64);
  __shared__ float red[4];
  if ((t & 63) == 0) red[t >> 6] = ss;
  __syncthreads();
  ss = red[0] + red[1] + red[2] + red[3];
  float scale = rsqrtf(ss * (1.0f / D_MODEL) + 1.1920929e-07f);
  f32x4 w0 = ((const f32x4*)w)[t];
  f32x4 w1 = ((const f32x4*)w)[256 + t];
  s16x4 o0, o1;
  #pragma unroll
  for (int i = 0; i < 4; i++) {
    o0[i] = f2bf(v0[i] * scale * w0[i]);
    o1[i] = f2bf(v1[i] * scale * w1[i]);
  }
  short* orow = out + (long)row * D_MODEL;
  ((s16x4*)orow)[t] = o0;
  ((s16x4*)orow)[256 + t] = o1;
}

// ---------------- RoPE in-place on q and k (bf16), grid (S, 2) ----------------
__global__ void rope_kernel(short* __restrict__ q, short* __restrict__ k,
                            const float* __restrict__ cosb, const float* __restrict__ sinb) {
  short* buf = blockIdx.y ? k : q;
  const int s = blockIdx.x;
  const int j = threadIdx.x * 4;   // 0..1023
  f32x4 c = *(const f32x4*)(cosb + (long)s * (D_MODEL / 2) + j);
  f32x4 sn = *(const f32x4*)(sinb + (long)s * (D_MODEL / 2) + j);
  short* row = buf + (long)s * D_MODEL;
  s16x4 x1 = *(s16x4*)(row + j);
  s16x4 x2 = *(s16x4*)(row + (D_MODEL / 2) + j);
  s16x4 o1, o2;
  #pragma unroll
  for (int i = 0; i < 4; i++) {
    float a = bf2f(x1[i]), b = bf2f(x2[i]);
    o1[i] = f2bf(a * c[i] - b * sn[i]);
    o2[i] = f2bf(a * sn[i] + b * c[i]);
  }
  *(s16x4*)(row + j) = o1;
  *(s16x4*)(row + (D_MODEL / 2) + j) = o2;
}

// ---------------- bf16 transpose [R][C] -> [C][R], tile 32x32 ----------------
__global__ void transpose_kernel(const short* __restrict__ in, short* __restrict__ out,
                                 int R, int C) {
  __shared__ short tile[32][33];
  const int bx = blockIdx.x * 32, by = blockIdx.y * 32;
  const int x = threadIdx.x, y = threadIdx.y;
  #pragma unroll
  for (int i = 0; i < 32; i += 8) tile[y + i][x] = in[(long)(by + y + i) * C + bx + x];
  __syncthreads();
  #pragma unroll
  for (int i = 0; i < 32; i += 8) out[(long)(bx + y + i) * R + by + x] = tile[x][y + i];
}

// ---------------- row softmax: fp32 [S,S] -> bf16 [S,S], block per row ----------------
__global__ void softmax_kernel(const float* __restrict__ sraw, short* __restrict__ pb) {
  const int row = blockIdx.x;
  const int t = threadIdx.x;
  const float* rp = sraw + (long)row * S_LEN;
  f32x4 v[4];
  #pragma unroll
  for (int i = 0; i < 4; i++) v[i] = ((const f32x4*)rp)[i * 256 + t];
  float m = -1e30f;
  #pragma unroll
  for (int i = 0; i < 4; i++)
    m = fmaxf(m, fmaxf(fmaxf(v[i][0], v[i][1]), fmaxf(v[i][2], v[i][3])));
  #pragma unroll
  for (int o = 32; o > 0; o >>= 1) m = fmaxf(m, __shfl_xor(m, o, 64));
  __shared__ float redm[4], reds[4];
  if ((t & 63) == 0) redm[t >> 6] = m;
  __syncthreads();
  m = fmaxf(fmaxf(redm[0], redm[1]), fmaxf(redm[2], redm[3]));
  float sum = 0.f;
  #pragma unroll
  for (int i = 0; i < 4; i++) {
    #pragma unroll
    for (int j = 0; j < 4; j++) { v[i][j] = __expf(v[i][j] - m); sum += v[i][j]; }
  }
  #pragma unroll
  for (int o = 32; o > 0; o >>= 1) sum += __shfl_xor(sum, o, 64);
  if ((t & 63) == 0) reds[t >> 6] = sum;
  __syncthreads();
  sum = reds[0] + reds[1] + reds[2] + reds[3];
  float inv = 1.0f / sum;
  short* prow = pb + (long)row * S_LEN;
  #pragma unroll
  for (int i = 0; i < 4; i++) {
    s16x4 o;
    #pragma unroll
    for (int j = 0; j < 4; j++) o[j] = f2bf(v[i][j] * inv);
    ((s16x4*)prow)[i * 256 + t] = o;
  }
}

// ---------------- GEMM: C[M,N] = A[M,K](bf16) x B[N,K](bf16)^T, m97 structure ----------------
// EPI: 0 = store bf16; 1 = store bf16 silu; 2 = store bf16 (gmul[idx] * acc);
//      3 = store fp32 acc*scale; 4 = store fp32 res[idx] + acc
template <int EPI>
__global__ __launch_bounds__(256)
void gemm_bt(const short* __restrict__ A, const short* __restrict__ B,
             float* __restrict__ Cf, short* __restrict__ Cb,
             const float* __restrict__ res, const short* __restrict__ gmul,
             int M, int N, int K, float scale) {
  __shared__ short As[128 * 32];
  __shared__ short Bs[128 * 32];
  const int t = threadIdx.x;
  const int lane = t & 63;
  const int wid = t >> 6;
  const int wr = wid >> 1, wc = wid & 1;
  const int llo = lane & 15, lhi = lane >> 4;
  const long m0 = (long)blockIdx.y * 128;
  const long n0 = (long)blockIdx.x * 128;

  f32x4 acc[4][4];
  #pragma unroll
  for (int i = 0; i < 4; i++)
    #pragma unroll
    for (int j = 0; j < 4; j++) acc[i][j] = (f32x4)(0.f);

  const int ci0 = t, ci1 = t + 256;
  const long ar0 = (m0 + (ci0 >> 2)) * (long)K, ar1 = (m0 + (ci1 >> 2)) * (long)K;
  const long br0 = (n0 + (ci0 >> 2)) * (long)K, br1 = (n0 + (ci1 >> 2)) * (long)K;
  const int cc0 = (ci0 & 3) * 8, cc1 = (ci1 & 3) * 8;

  for (int kt = 0; kt < K; kt += 32) {
    __syncthreads();
    GLDS16(A + ar0 + kt + cc0, As + ci0 * 8);
    GLDS16(A + ar1 + kt + cc1, As + ci1 * 8);
    GLDS16(B + br0 + kt + cc0, Bs + ci0 * 8);
    GLDS16(B + br1 + kt + cc1, Bs + ci1 * 8);
    __syncthreads();
    s16x8 af[4], bfr[4];
    #pragma unroll
    for (int f = 0; f < 4; f++) {
      af[f]  = *(const s16x8*)(As + (wr * 64 + f * 16 + llo) * 32 + lhi * 8);
      bfr[f] = *(const s16x8*)(Bs + (wc * 64 + f * 16 + llo) * 32 + lhi * 8);
    }
    #pragma unroll
    for (int i = 0; i < 4; i++)
      #pragma unroll
      for (int j = 0; j < 4; j++)
        acc[i][j] = __builtin_amdgcn_mfma_f32_16x16x32_bf16(af[i], bfr[j], acc[i][j], 0, 0, 0);
  }

  #pragma unroll
  for (int i = 0; i < 4; i++) {
    #pragma unroll
    for (int j = 0; j < 4; j++) {
      const long row = m0 + wr * 64 + i * 16 + lhi * 4;
      const long col = n0 + wc * 64 + j * 16 + llo;
      #pragma unroll
      for (int r = 0; r < 4; r++) {
        float v = acc[i][j][r];
        long idx = (row + r) * (long)N + col;
        if (EPI == 0) {
          Cb[idx] = f2bf(v);
        } else if (EPI == 1) {
          Cb[idx] = f2bf(v / (1.0f + __expf(-v)));
        } else if (EPI == 2) {
          Cb[idx] = f2bf(bf2f(gmul[idx]) * v);
        } else if (EPI == 3) {
          Cf[idx] = v * scale;
        } else {
          Cf[idx] = res[idx] + v;
        }
      }
    }
  }
}

extern "C" void kernel_launch(void* const* d_in, const int* in_sizes, int n_in,
                              void* d_out, int out_size, void* d_ws, size_t ws_size,
                              hipStream_t stream) {
  const float* x      = (const float*)d_in[0];
  const float* w_rn1  = (const float*)d_in[1];
  const float* wq     = (const float*)d_in[2];
  const float* wk     = (const float*)d_in[3];
  const float* wv     = (const float*)d_in[4];
  const float* wo     = (const float*)d_in[5];
  const float* w_rn2  = (const float*)d_in[6];
  const float* w_gate = (const float*)d_in[7];
  const float* w_up   = (const float*)d_in[8];
  const float* w_down = (const float*)d_in[9];
  const float* cosb   = (const float*)d_in[10];
  const float* sinb   = (const float*)d_in[11];
  float* out = (float*)d_out;

  const long S = S_LEN, D = D_MODEL, FF = FF_DIM;
  char* ws = (char*)d_ws;
  size_t off = 0;
  auto alloc = [&](size_t bytes) { void* p = ws + off; off += (bytes + 255) & ~(size_t)255; return p; };

  short* qb    = (short*)alloc(S * D * 2);         // q (bf16)
  short* kb    = (short*)alloc(S * D * 2);         // k
  short* vT    = (short*)alloc(D * S * 2);         // v transposed [D][S]
  short* hb    = (short*)alloc(S * D * 2);         // rmsnorm out (reused for rms2)
  float* x1    = (float*)alloc(S * D * 4);         // residual-1 (fp32)
  short* wbuf  = (short*)alloc(FF * D * 2);        // converted weight slot (max size)
  short* vb_ao = (short*)alloc(S * D * 2);         // v, later attn-out
  char*  u2    = (char*)alloc(S * S * 4);          // scores fp32, later SwiGLU bf16 [S,FF]
  float* sraw  = (float*)u2;
  short* gbuf  = (short*)u2;
  short* pb    = (short*)alloc(S * S * 2);         // probabilities bf16

  const float inv_scale = 1.0f / sqrtf((float)D_MODEL);
  const long DD = D * D, FD = FF * D;
  const int convDD = (int)(DD / 8 / 256), convFD = (int)(FD / 8 / 256);
  dim3 blk(256);
  dim3 gD(D_MODEL / 128, S_LEN / 128);   // N=2048 GEMMs
  dim3 gS(S_LEN / 128, S_LEN / 128);     // N=4096 (scores)
  dim3 gF(FF_DIM / 128, S_LEN / 128);    // N=8192 (gate/up)

  // 1. rms1
  rmsnorm_kernel<<<S_LEN, 256, 0, stream>>>(x, w_rn1, hb);
  // 2-4. q, k, v projections
  conv_f32_bf16<<<convDD, blk, 0, stream>>>(wq, wbuf, DD);
  gemm_bt<0><<<gD, blk, 0, stream>>>(hb, wbuf, nullptr, qb, nullptr, nullptr, S_LEN, D_MODEL, D_MODEL, 1.f);
  conv_f32_bf16<<<convDD, blk, 0, stream>>>(wk, wbuf, DD);
  gemm_bt<0><<<gD, blk, 0, stream>>>(hb, wbuf, nullptr, kb, nullptr, nullptr, S_LEN, D_MODEL, D_MODEL, 1.f);
  conv_f32_bf16<<<convDD, blk, 0, stream>>>(wv, wbuf, DD);
  gemm_bt<0><<<gD, blk, 0, stream>>>(hb, wbuf, nullptr, vb_ao, nullptr, nullptr, S_LEN, D_MODEL, D_MODEL, 1.f);
  // 5. RoPE on q, k
  rope_kernel<<<dim3(S_LEN, 2), blk, 0, stream>>>(qb, kb, cosb, sinb);
  // 6. v -> vT
  transpose_kernel<<<dim3(D_MODEL / 32, S_LEN / 32), dim3(32, 8), 0, stream>>>(vb_ao, vT, S_LEN, D_MODEL);
  // 7. scores = q k^T / sqrt(D)  (fp32)
  gemm_bt<3><<<gS, blk, 0, stream>>>(qb, kb, sraw, nullptr, nullptr, nullptr, S_LEN, S_LEN, D_MODEL, inv_scale);
  // 8. softmax -> pb (bf16)
  softmax_kernel<<<S_LEN, 256, 0, stream>>>(sraw, pb);
  // 9. attn out = P @ V   (A=pb, B=vT)
  gemm_bt<0><<<gD, blk, 0, stream>>>(pb, vT, nullptr, vb_ao, nullptr, nullptr, S_LEN, D_MODEL, S_LEN, 1.f);
  // 10. x1 = x + ao @ wo^T
  conv_f32_bf16<<<convDD, blk, 0, stream>>>(wo, wbuf, DD);
  gemm_bt<4><<<gD, blk, 0, stream>>>(vb_ao, wbuf, x1, nullptr, x, nullptr, S_LEN, D_MODEL, D_MODEL, 1.f);
  // 11. rms2
  rmsnorm_kernel<<<S_LEN, 256, 0, stream>>>(x1, w_rn2, hb);
  // 12. gate = silu(h @ wg^T)
  conv_f32_bf16<<<convFD, blk, 0, stream>>>(w_gate, wbuf, FD);
  gemm_bt<1><<<gF, blk, 0, stream>>>(hb, wbuf, nullptr, gbuf, nullptr, nullptr, S_LEN, FF_DIM, D_MODEL, 1.f);
  // 13. g = gate * (h @ wu^T)   (in place on gbuf)
  conv_f32_bf16<<<convFD, blk, 0, stream>>>(w_up, wbuf, FD);
  gemm_bt<2><<<gF, blk, 0, stream>>>(hb, wbuf, nullptr, gbuf, nullptr, gbuf, S_LEN, FF_DIM, D_MODEL, 1.f);
  // 14. out = x1 + g @ wd^T
  conv_f32_bf16<<<convFD, blk, 0, stream>>>(w_down, wbuf, FD);
  gemm_bt<4><<<gD, blk, 0, stream>>>(gbuf, wbuf, out, nullptr, x1, nullptr, S_LEN, D_MODEL, FF_DIM, 1.f);
}

// Round 2
// 1032.539 us; speedup vs baseline: 1.1252x; 1.1252x over previous
//
#include <hip/hip_runtime.h>

#define S_LEN 4096
#define D_MODEL 2048
#define FF_DIM 8192

typedef __attribute__((ext_vector_type(8))) short s16x8;
typedef __attribute__((ext_vector_type(4))) short s16x4;
typedef __attribute__((ext_vector_type(4))) float f32x4;

__device__ __forceinline__ short f2bf(float f) {
  union { float f; unsigned u; } c; c.f = f;
  unsigned r = (c.u + 0x7fffu + ((c.u >> 16) & 1u)) >> 16;
  return (short)r;
}
__device__ __forceinline__ float bf2f(short s) {
  union { unsigned u; float f; } c; c.u = ((unsigned)(unsigned short)s) << 16;
  return c.f;
}

#define GLDS16(g, l) __builtin_amdgcn_global_load_lds( \
    (const __attribute__((address_space(1))) unsigned*)(g), \
    (__attribute__((address_space(3))) unsigned*)(l), 16, 0, 0)

// ---------------- fp32 -> bf16 bulk convert (n multiple of 8) ----------------
__global__ void conv_f32_bf16(const float* __restrict__ in, short* __restrict__ out, long n) {
  long i = ((long)blockIdx.x * blockDim.x + threadIdx.x) * 8;
  if (i >= n) return;
  f32x4 a = *(const f32x4*)(in + i);
  f32x4 b = *(const f32x4*)(in + i + 4);
  s16x8 o;
  o[0] = f2bf(a[0]); o[1] = f2bf(a[1]); o[2] = f2bf(a[2]); o[3] = f2bf(a[3]);
  o[4] = f2bf(b[0]); o[5] = f2bf(b[1]); o[6] = f2bf(b[2]); o[7] = f2bf(b[3]);
  *(s16x8*)(out + i) = o;
}

// ---------------- RMSNorm: fp32 [S,D=2048] -> bf16, block per row ----------------
__global__ void rmsnorm_kernel(const float* __restrict__ x, const float* __restrict__ w,
                               short* __restrict__ out) {
  const int row = blockIdx.x;
  const int t = threadIdx.x;
  const float* xr = x + (long)row * D_MODEL;
  f32x4 v0 = ((const f32x4*)xr)[t];
  f32x4 v1 = ((const f32x4*)xr)[256 + t];
  float ss = v0[0]*v0[0] + v0[1]*v0[1] + v0[2]*v0[2] + v0[3]*v0[3]
           + v1[0]*v1[0] + v1[1]*v1[1] + v1[2]*v1[2] + v1[3]*v1[3];
  #pragma unroll
  for (int o = 32; o > 0; o >>= 1) ss += __shfl_xor(ss, o, 64);
  __shared__ float red[4];
  if ((t & 63) == 0) red[t >> 6] = ss;
  __syncthreads();
  ss = red[0] + red[1] + red[2] + red[3];
  float scale = rsqrtf(ss * (1.0f / D_MODEL) + 1.1920929e-07f);
  f32x4 w0 = ((const f32x4*)w)[t];
  f32x4 w1 = ((const f32x4*)w)[256 + t];
  s16x4 o0, o1;
  #pragma unroll
  for (int i = 0; i < 4; i++) {
    o0[i] = f2bf(v0[i] * scale * w0[i]);
    o1[i] = f2bf(v1[i] * scale * w1[i]);
  }
  short* orow = out + (long)row * D_MODEL;
  ((s16x4*)orow)[t] = o0;
  ((s16x4*)orow)[256 + t] = o1;
}

// ---------------- RoPE in-place on q and k (bf16), grid (S, 2) ----------------
__global__ void rope_kernel(short* __restrict__ q, short* __restrict__ k,
                            const float* __restrict__ cosb, const float* __restrict__ sinb) {
  short* buf = blockIdx.y ? k : q;
  const int s = blockIdx.x;
  const int j = threadIdx.x * 4;   // 0..1023
  f32x4 c = *(const f32x4*)(cosb + (long)s * (D_MODEL / 2) + j);
  f32x4 sn = *(const f32x4*)(sinb + (long)s * (D_MODEL / 2) + j);
  short* row = buf + (long)s * D_MODEL;
  s16x4 x1 = *(s16x4*)(row + j);
  s16x4 x2 = *(s16x4*)(row + (D_MODEL / 2) + j);
  s16x4 o1, o2;
  #pragma unroll
  for (int i = 0; i < 4; i++) {
    float a = bf2f(x1[i]), b = bf2f(x2[i]);
    o1[i] = f2bf(a * c[i] - b * sn[i]);
    o2[i] = f2bf(a * sn[i] + b * c[i]);
  }
  *(s16x4*)(row + j) = o1;
  *(s16x4*)(row + (D_MODEL / 2) + j) = o2;
}

// ---------------- bf16 transpose [R][C] -> [C][R], tile 32x32 ----------------
__global__ void transpose_kernel(const short* __restrict__ in, short* __restrict__ out,
                                 int R, int C) {
  __shared__ short tile[32][33];
  const int bx = blockIdx.x * 32, by = blockIdx.y * 32;
  const int x = threadIdx.x, y = threadIdx.y;
  #pragma unroll
  for (int i = 0; i < 32; i += 8) tile[y + i][x] = in[(long)(by + y + i) * C + bx + x];
  __syncthreads();
  #pragma unroll
  for (int i = 0; i < 32; i += 8) out[(long)(bx + y + i) * R + by + x] = tile[x][y + i];
}

// ---------------- row softmax: fp32 [S,S] -> bf16 [S,S], block per row ----------------
__global__ void softmax_kernel(const float* __restrict__ sraw, short* __restrict__ pb) {
  const int row = blockIdx.x;
  const int t = threadIdx.x;
  const float* rp = sraw + (long)row * S_LEN;
  f32x4 v[4];
  #pragma unroll
  for (int i = 0; i < 4; i++) v[i] = ((const f32x4*)rp)[i * 256 + t];
  float m = -1e30f;
  #pragma unroll
  for (int i = 0; i < 4; i++)
    m = fmaxf(m, fmaxf(fmaxf(v[i][0], v[i][1]), fmaxf(v[i][2], v[i][3])));
  #pragma unroll
  for (int o = 32; o > 0; o >>= 1) m = fmaxf(m, __shfl_xor(m, o, 64));
  __shared__ float redm[4], reds[4];
  if ((t & 63) == 0) redm[t >> 6] = m;
  __syncthreads();
  m = fmaxf(fmaxf(redm[0], redm[1]), fmaxf(redm[2], redm[3]));
  float sum = 0.f;
  #pragma unroll
  for (int i = 0; i < 4; i++) {
    #pragma unroll
    for (int j = 0; j < 4; j++) { v[i][j] = __expf(v[i][j] - m); sum += v[i][j]; }
  }
  #pragma unroll
  for (int o = 32; o > 0; o >>= 1) sum += __shfl_xor(sum, o, 64);
  if ((t & 63) == 0) reds[t >> 6] = sum;
  __syncthreads();
  sum = reds[0] + reds[1] + reds[2] + reds[3];
  float inv = 1.0f / sum;
  short* prow = pb + (long)row * S_LEN;
  #pragma unroll
  for (int i = 0; i < 4; i++) {
    s16x4 o;
    #pragma unroll
    for (int j = 0; j < 4; j++) o[j] = f2bf(v[i][j] * inv);
    ((s16x4*)prow)[i * 256 + t] = o;
  }
}

// ============ Pipelined GEMM: 256x256 tile, 8 waves, K32 4-slot ring ============
// C[M,N] = A[M,K] x B[N,K]^T (bf16 in). EPI: 0 bf16; 1 bf16 silu; 2 bf16 gmul*acc;
// 3 fp32 acc*scale.
template <int EPI>
__global__ __launch_bounds__(512)
void gemm_pipe(const short* __restrict__ A, const short* __restrict__ B,
               float* __restrict__ Cf, short* __restrict__ Cb,
               const short* __restrict__ gmul,
               int M, int N, int K, float scale) {
  __shared__ short lds[4][2][256 * 32];   // [slot][A/B][row*32 + k]
  const int t = threadIdx.x;
  const int lane = t & 63, wid = t >> 6;
  const int wr = wid >> 2, wc = wid & 3;           // 2 x 4 waves
  const int llo = lane & 15, lhi = lane >> 4;
  const long m0 = (long)blockIdx.y * 256;
  const long n0 = (long)blockIdx.x * 256;

  // staging address precompute: chunk c covers LDS bytes [c*16, c*16+16)
  // row = c>>2 (0..255), 16B-quarter = c&3
  const int c0 = t, c1 = t + 512;
  const long aoff0 = (m0 + (c0 >> 2)) * (long)K + (c0 & 3) * 8;
  const long aoff1 = (m0 + (c1 >> 2)) * (long)K + (c1 & 3) * 8;
  const long boff0 = (n0 + (c0 >> 2)) * (long)K + (c0 & 3) * 8;
  const long boff1 = (n0 + (c1 >> 2)) * (long)K + (c1 & 3) * 8;

  f32x4 acc[8][4];
  #pragma unroll
  for (int m = 0; m < 8; m++)
    #pragma unroll
    for (int n = 0; n < 4; n++) acc[m][n] = (f32x4)(0.f);

  auto stage = [&](int ks) {
    const int slot = ks & 3;
    short* la = (short*)lds[slot][0];
    short* lb = (short*)lds[slot][1];
    const long kb_ = (long)ks * 32;
    GLDS16(A + aoff0 + kb_, la + c0 * 8);
    GLDS16(A + aoff1 + kb_, la + c1 * 8);
    GLDS16(B + boff0 + kb_, lb + c0 * 8);
    GLDS16(B + boff1 + kb_, lb + c1 * 8);
  };

  auto phase_compute = [&](int ks) {
    const int slot = ks & 3;
    const short* la = (const short*)lds[slot][0];
    const short* lb = (const short*)lds[slot][1];
    s16x8 af[8], bf[4];
    #pragma unroll
    for (int m = 0; m < 8; m++)
      af[m] = *(const s16x8*)(la + (wr * 128 + m * 16 + llo) * 32 + lhi * 8);
    #pragma unroll
    for (int n = 0; n < 4; n++)
      bf[n] = *(const s16x8*)(lb + (wc * 64 + n * 16 + llo) * 32 + lhi * 8);
    __builtin_amdgcn_s_setprio(1);
    #pragma unroll
    for (int m = 0; m < 8; m++)
      #pragma unroll
      for (int n = 0; n < 4; n++)
        acc[m][n] = __builtin_amdgcn_mfma_f32_16x16x32_bf16(af[m], bf[n], acc[m][n], 0, 0, 0);
    __builtin_amdgcn_s_setprio(0);
  };

  const int NPH = K >> 5;   // K / 32, always >= 4 here
  stage(0); stage(1); stage(2);
  asm volatile("s_waitcnt vmcnt(8)" ::: "memory");
  __builtin_amdgcn_s_barrier();
  for (int p = 0; p < NPH - 3; ++p) {
    stage(p + 3);               // issue next stages first (hide HBM latency)
    phase_compute(p);
    asm volatile("s_waitcnt vmcnt(8)" ::: "memory");   // slot p+1 landed
    __builtin_amdgcn_s_barrier();
  }
  phase_compute(NPH - 3);
  asm volatile("s_waitcnt vmcnt(4)" ::: "memory");
  __builtin_amdgcn_s_barrier();
  phase_compute(NPH - 2);
  asm volatile("s_waitcnt vmcnt(0)" ::: "memory");
  __builtin_amdgcn_s_barrier();
  phase_compute(NPH - 1);

  // epilogue: C row = m0 + wr*128 + m*16 + lhi*4 + r ; col = n0 + wc*64 + n*16 + llo
  #pragma unroll
  for (int m = 0; m < 8; m++) {
    const long row0 = m0 + wr * 128 + m * 16 + lhi * 4;
    #pragma unroll
    for (int n = 0; n < 4; n++) {
      const long col = n0 + wc * 64 + n * 16 + llo;
      #pragma unroll
      for (int r = 0; r < 4; r++) {
        float v = acc[m][n][r];
        long idx = (row0 + r) * (long)N + col;
        if (EPI == 0) {
          Cb[idx] = f2bf(v);
        } else if (EPI == 1) {
          Cb[idx] = f2bf(v / (1.0f + __expf(-v)));
        } else if (EPI == 2) {
          Cb[idx] = f2bf(bf2f(gmul[idx]) * v);
        } else {
          Cf[idx] = v * scale;
        }
      }
    }
  }
}

// ---------------- GEMM: m97 structure (kept for N=2048 shapes) ----------------
// EPI: 0 = store bf16; 4 = store fp32 res[idx] + acc
template <int EPI>
__global__ __launch_bounds__(256)
void gemm_bt(const short* __restrict__ A, const short* __restrict__ B,
             float* __restrict__ Cf, short* __restrict__ Cb,
             const float* __restrict__ res,
             int M, int N, int K) {
  __shared__ short As[128 * 32];
  __shared__ short Bs[128 * 32];
  const int t = threadIdx.x;
  const int lane = t & 63;
  const int wid = t >> 6;
  const int wr = wid >> 1, wc = wid & 1;
  const int llo = lane & 15, lhi = lane >> 4;
  const long m0 = (long)blockIdx.y * 128;
  const long n0 = (long)blockIdx.x * 128;

  f32x4 acc[4][4];
  #pragma unroll
  for (int i = 0; i < 4; i++)
    #pragma unroll
    for (int j = 0; j < 4; j++) acc[i][j] = (f32x4)(0.f);

  const int ci0 = t, ci1 = t + 256;
  const long ar0 = (m0 + (ci0 >> 2)) * (long)K, ar1 = (m0 + (ci1 >> 2)) * (long)K;
  const long br0 = (n0 + (ci0 >> 2)) * (long)K, br1 = (n0 + (ci1 >> 2)) * (long)K;
  const int cc0 = (ci0 & 3) * 8, cc1 = (ci1 & 3) * 8;

  for (int kt = 0; kt < K; kt += 32) {
    __syncthreads();
    GLDS16(A + ar0 + kt + cc0, As + ci0 * 8);
    GLDS16(A + ar1 + kt + cc1, As + ci1 * 8);
    GLDS16(B + br0 + kt + cc0, Bs + ci0 * 8);
    GLDS16(B + br1 + kt + cc1, Bs + ci1 * 8);
    __syncthreads();
    s16x8 af[4], bfr[4];
    #pragma unroll
    for (int f = 0; f < 4; f++) {
      af[f]  = *(const s16x8*)(As + (wr * 64 + f * 16 + llo) * 32 + lhi * 8);
      bfr[f] = *(const s16x8*)(Bs + (wc * 64 + f * 16 + llo) * 32 + lhi * 8);
    }
    #pragma unroll
    for (int i = 0; i < 4; i++)
      #pragma unroll
      for (int j = 0; j < 4; j++)
        acc[i][j] = __builtin_amdgcn_mfma_f32_16x16x32_bf16(af[i], bfr[j], acc[i][j], 0, 0, 0);
  }

  #pragma unroll
  for (int i = 0; i < 4; i++) {
    #pragma unroll
    for (int j = 0; j < 4; j++) {
      const long row = m0 + wr * 64 + i * 16 + lhi * 4;
      const long col = n0 + wc * 64 + j * 16 + llo;
      #pragma unroll
      for (int r = 0; r < 4; r++) {
        float v = acc[i][j][r];
        long idx = (row + r) * (long)N + col;
        if (EPI == 0) {
          Cb[idx] = f2bf(v);
        } else {
          Cf[idx] = res[idx] + v;
        }
      }
    }
  }
}

extern "C" void kernel_launch(void* const* d_in, const int* in_sizes, int n_in,
                              void* d_out, int out_size, void* d_ws, size_t ws_size,
                              hipStream_t stream) {
  const float* x      = (const float*)d_in[0];
  const float* w_rn1  = (const float*)d_in[1];
  const float* wq     = (const float*)d_in[2];
  const float* wk     = (const float*)d_in[3];
  const float* wv     = (const float*)d_in[4];
  const float* wo     = (const float*)d_in[5];
  const float* w_rn2  = (const float*)d_in[6];
  const float* w_gate = (const float*)d_in[7];
  const float* w_up   = (const float*)d_in[8];
  const float* w_down = (const float*)d_in[9];
  const float* cosb   = (const float*)d_in[10];
  const float* sinb   = (const float*)d_in[11];
  float* out = (float*)d_out;

  const long S = S_LEN, D = D_MODEL, FF = FF_DIM;
  char* ws = (char*)d_ws;
  size_t off = 0;
  auto alloc = [&](size_t bytes) { void* p = ws + off; off += (bytes + 255) & ~(size_t)255; return p; };

  short* qb    = (short*)alloc(S * D * 2);         // q (bf16)
  short* kb    = (short*)alloc(S * D * 2);         // k
  short* vT    = (short*)alloc(D * S * 2);         // v transposed [D][S]
  short* hb    = (short*)alloc(S * D * 2);         // rmsnorm out (reused for rms2)
  float* x1    = (float*)alloc(S * D * 4);         // residual-1 (fp32)
  short* wbuf  = (short*)alloc(FF * D * 2);        // converted weight slot (max size)
  short* vb_ao = (short*)alloc(S * D * 2);         // v, later attn-out
  char*  u2    = (char*)alloc(S * S * 4);          // scores fp32, later SwiGLU bf16 [S,FF]
  float* sraw  = (float*)u2;
  short* gbuf  = (short*)u2;
  short* pb    = (short*)alloc(S * S * 2);         // probabilities bf16

  const float inv_scale = 1.0f / sqrtf((float)D_MODEL);
  const long DD = D * D, FD = FF * D;
  const int convDD = (int)(DD / 8 / 256), convFD = (int)(FD / 8 / 256);
  dim3 blk(256), blk5(512);
  dim3 gD(D_MODEL / 128, S_LEN / 128);     // m97 GEMMs, N=2048
  dim3 gS2(S_LEN / 256, S_LEN / 256);      // scores 256-tile: 16x16
  dim3 gP2(D_MODEL / 256, S_LEN / 256);    // PV 256-tile: 8x16
  dim3 gF2(FF_DIM / 256, S_LEN / 256);     // gate/up 256-tile: 32x16

  // 1. rms1
  rmsnorm_kernel<<<S_LEN, 256, 0, stream>>>(x, w_rn1, hb);
  // 2-4. q, k, v projections (m97 kernel, N=2048)
  conv_f32_bf16<<<convDD, blk, 0, stream>>>(wq, wbuf, DD);
  gemm_bt<0><<<gD, blk, 0, stream>>>(hb, wbuf, nullptr, qb, nullptr, S_LEN, D_MODEL, D_MODEL);
  conv_f32_bf16<<<convDD, blk, 0, stream>>>(wk, wbuf, DD);
  gemm_bt<0><<<gD, blk, 0, stream>>>(hb, wbuf, nullptr, kb, nullptr, S_LEN, D_MODEL, D_MODEL);
  conv_f32_bf16<<<convDD, blk, 0, stream>>>(wv, wbuf, DD);
  gemm_bt<0><<<gD, blk, 0, stream>>>(hb, wbuf, nullptr, vb_ao, nullptr, S_LEN, D_MODEL, D_MODEL);
  // 5. RoPE on q, k
  rope_kernel<<<dim3(S_LEN, 2), blk, 0, stream>>>(qb, kb, cosb, sinb);
  // 6. v -> vT
  transpose_kernel<<<dim3(D_MODEL / 32, S_LEN / 32), dim3(32, 8), 0, stream>>>(vb_ao, vT, S_LEN, D_MODEL);
  // 7. scores = q k^T / sqrt(D)  (fp32) — pipelined
  gemm_pipe<3><<<gS2, blk5, 0, stream>>>(qb, kb, sraw, nullptr, nullptr, S_LEN, S_LEN, D_MODEL, inv_scale);
  // 8. softmax -> pb (bf16)
  softmax_kernel<<<S_LEN, 256, 0, stream>>>(sraw, pb);
  // 9. attn out = P @ V   (A=pb, B=vT) — pipelined
  gemm_pipe<0><<<gP2, blk5, 0, stream>>>(pb, vT, nullptr, vb_ao, nullptr, S_LEN, D_MODEL, S_LEN, 1.f);
  // 10. x1 = x + ao @ wo^T
  conv_f32_bf16<<<convDD, blk, 0, stream>>>(wo, wbuf, DD);
  gemm_bt<4><<<gD, blk, 0, stream>>>(vb_ao, wbuf, x1, nullptr, x, S_LEN, D_MODEL, D_MODEL);
  // 11. rms2
  rmsnorm_kernel<<<S_LEN, 256, 0, stream>>>(x1, w_rn2, hb);
  // 12. gate = silu(h @ wg^T) — pipelined
  conv_f32_bf16<<<convFD, blk, 0, stream>>>(w_gate, wbuf, FD);
  gemm_pipe<1><<<gF2, blk5, 0, stream>>>(hb, wbuf, nullptr, gbuf, nullptr, S_LEN, FF_DIM, D_MODEL, 1.f);
  // 13. g = gate * (h @ wu^T)   (in place on gbuf) — pipelined
  conv_f32_bf16<<<convFD, blk, 0, stream>>>(w_up, wbuf, FD);
  gemm_pipe<2><<<gF2, blk5, 0, stream>>>(hb, wbuf, nullptr, gbuf, gbuf, S_LEN, FF_DIM, D_MODEL, 1.f);
  // 14. out = x1 + g @ wd^T
  conv_f32_bf16<<<convFD, blk, 0, stream>>>(w_down, wbuf, FD);
  gemm_bt<4><<<gD, blk, 0, stream>>>(gbuf, wbuf, out, nullptr, x1, S_LEN, D_MODEL, FF_DIM);
}

// Round 3
// 889.935 us; speedup vs baseline: 1.3055x; 1.1602x over previous
//
#include <hip/hip_runtime.h>

#define S_LEN 4096
#define D_MODEL 2048
#define FF_DIM 8192
#define QKV_LD 6144

typedef __attribute__((ext_vector_type(8))) short s16x8;
typedef __attribute__((ext_vector_type(4))) short s16x4;
typedef __attribute__((ext_vector_type(4))) float f32x4;

__device__ __forceinline__ short f2bf(float f) {
  union { float f; unsigned u; } c; c.f = f;
  unsigned r = (c.u + 0x7fffu + ((c.u >> 16) & 1u)) >> 16;
  return (short)r;
}
__device__ __forceinline__ float bf2f(short s) {
  union { unsigned u; float f; } c; c.u = ((unsigned)(unsigned short)s) << 16;
  return c.f;
}

#define GLDS16(g, l) __builtin_amdgcn_global_load_lds( \
    (const __attribute__((address_space(1))) unsigned*)(g), \
    (__attribute__((address_space(3))) unsigned*)(l), 16, 0, 0)

template <int N> __device__ __forceinline__ void waitvm() {
  if constexpr (N == 0)      asm volatile("s_waitcnt vmcnt(0)" ::: "memory");
  else if constexpr (N == 3) asm volatile("s_waitcnt vmcnt(3)" ::: "memory");
  else if constexpr (N == 4) asm volatile("s_waitcnt vmcnt(4)" ::: "memory");
  else if constexpr (N == 6) asm volatile("s_waitcnt vmcnt(6)" ::: "memory");
  else                       asm volatile("s_waitcnt vmcnt(8)" ::: "memory");
}

// st_16x32 swizzle: XOR byte-bit-5 with byte-bit-9 (row bit 3 for 64B rows).
__device__ __forceinline__ int swz(int byte_off) {
  return byte_off ^ (((byte_off >> 9) & 1) << 5);
}

// ---------------- fp32 -> bf16 bulk convert (n multiple of 8) ----------------
__global__ void conv_f32_bf16(const float* __restrict__ in, short* __restrict__ out, long n) {
  long i = ((long)blockIdx.x * blockDim.x + threadIdx.x) * 8;
  if (i >= n) return;
  f32x4 a = *(const f32x4*)(in + i);
  f32x4 b = *(const f32x4*)(in + i + 4);
  s16x8 o;
  o[0] = f2bf(a[0]); o[1] = f2bf(a[1]); o[2] = f2bf(a[2]); o[3] = f2bf(a[3]);
  o[4] = f2bf(b[0]); o[5] = f2bf(b[1]); o[6] = f2bf(b[2]); o[7] = f2bf(b[3]);
  *(s16x8*)(out + i) = o;
}

// ---------------- RMSNorm: fp32 [S,D=2048] -> bf16, block per row ----------------
__global__ void rmsnorm_kernel(const float* __restrict__ x, const float* __restrict__ w,
                               short* __restrict__ out) {
  const int row = blockIdx.x;
  const int t = threadIdx.x;
  const float* xr = x + (long)row * D_MODEL;
  f32x4 v0 = ((const f32x4*)xr)[t];
  f32x4 v1 = ((const f32x4*)xr)[256 + t];
  float ss = v0[0]*v0[0] + v0[1]*v0[1] + v0[2]*v0[2] + v0[3]*v0[3]
           + v1[0]*v1[0] + v1[1]*v1[1] + v1[2]*v1[2] + v1[3]*v1[3];
  #pragma unroll
  for (int o = 32; o > 0; o >>= 1) ss += __shfl_xor(ss, o, 64);
  __shared__ float red[4];
  if ((t & 63) == 0) red[t >> 6] = ss;
  __syncthreads();
  ss = red[0] + red[1] + red[2] + red[3];
  float scale = rsqrtf(ss * (1.0f / D_MODEL) + 1.1920929e-07f);
  f32x4 w0 = ((const f32x4*)w)[t];
  f32x4 w1 = ((const f32x4*)w)[256 + t];
  s16x4 o0, o1;
  #pragma unroll
  for (int i = 0; i < 4; i++) {
    o0[i] = f2bf(v0[i] * scale * w0[i]);
    o1[i] = f2bf(v1[i] * scale * w1[i]);
  }
  short* orow = out + (long)row * D_MODEL;
  ((s16x4*)orow)[t] = o0;
  ((s16x4*)orow)[256 + t] = o1;
}

// ---------------- RoPE in-place on q,k columns of qkv [S][6144], grid (S, 2) ----------------
__global__ void rope_kernel(short* __restrict__ qkv,
                            const float* __restrict__ cosb, const float* __restrict__ sinb) {
  const int s = blockIdx.x;
  short* row = qkv + (long)s * QKV_LD + (blockIdx.y ? D_MODEL : 0);
  const int j = threadIdx.x * 4;   // 0..1023
  f32x4 c = *(const f32x4*)(cosb + (long)s * (D_MODEL / 2) + j);
  f32x4 sn = *(const f32x4*)(sinb + (long)s * (D_MODEL / 2) + j);
  s16x4 x1 = *(s16x4*)(row + j);
  s16x4 x2 = *(s16x4*)(row + (D_MODEL / 2) + j);
  s16x4 o1, o2;
  #pragma unroll
  for (int i = 0; i < 4; i++) {
    float a = bf2f(x1[i]), b = bf2f(x2[i]);
    o1[i] = f2bf(a * c[i] - b * sn[i]);
    o2[i] = f2bf(a * sn[i] + b * c[i]);
  }
  *(s16x4*)(row + j) = o1;
  *(s16x4*)(row + (D_MODEL / 2) + j) = o2;
}

// ---------------- bf16 transpose [R][C] (row stride ld) -> [C][R], tile 32x32 ----------------
__global__ void transpose_kernel(const short* __restrict__ in, short* __restrict__ out,
                                 int R, int C, int ld) {
  __shared__ short tile[32][33];
  const int bx = blockIdx.x * 32, by = blockIdx.y * 32;
  const int x = threadIdx.x, y = threadIdx.y;
  #pragma unroll
  for (int i = 0; i < 32; i += 8) tile[y + i][x] = in[(long)(by + y + i) * ld + bx + x];
  __syncthreads();
  #pragma unroll
  for (int i = 0; i < 32; i += 8) out[(long)(bx + y + i) * R + by + x] = tile[x][y + i];
}

// ---------------- row softmax: fp32 [S,S] -> bf16 [S,S], block per row ----------------
__global__ void softmax_kernel(const float* __restrict__ sraw, short* __restrict__ pb) {
  const int row = blockIdx.x;
  const int t = threadIdx.x;
  const float* rp = sraw + (long)row * S_LEN;
  f32x4 v[4];
  #pragma unroll
  for (int i = 0; i < 4; i++) v[i] = ((const f32x4*)rp)[i * 256 + t];
  float m = -1e30f;
  #pragma unroll
  for (int i = 0; i < 4; i++)
    m = fmaxf(m, fmaxf(fmaxf(v[i][0], v[i][1]), fmaxf(v[i][2], v[i][3])));
  #pragma unroll
  for (int o = 32; o > 0; o >>= 1) m = fmaxf(m, __shfl_xor(m, o, 64));
  __shared__ float redm[4], reds[4];
  if ((t & 63) == 0) redm[t >> 6] = m;
  __syncthreads();
  m = fmaxf(fmaxf(redm[0], redm[1]), fmaxf(redm[2], redm[3]));
  float sum = 0.f;
  #pragma unroll
  for (int i = 0; i < 4; i++) {
    #pragma unroll
    for (int j = 0; j < 4; j++) { v[i][j] = __expf(v[i][j] - m); sum += v[i][j]; }
  }
  #pragma unroll
  for (int o = 32; o > 0; o >>= 1) sum += __shfl_xor(sum, o, 64);
  if ((t & 63) == 0) reds[t >> 6] = sum;
  __syncthreads();
  sum = reds[0] + reds[1] + reds[2] + reds[3];
  float inv = 1.0f / sum;
  short* prow = pb + (long)row * S_LEN;
  #pragma unroll
  for (int i = 0; i < 4; i++) {
    s16x4 o;
    #pragma unroll
    for (int j = 0; j < 4; j++) o[j] = f2bf(v[i][j] * inv);
    ((s16x4*)prow)[i * 256 + t] = o;
  }
}

// ============ Pipelined GEMM: BM=256 x BN tile, 8 waves, K32 4-slot ring, T2 swizzle ============
// C[M,N] = A[M,K] x B[N,K]^T (bf16 in, strided lda/ldb/ldc).
// EPI: 0 bf16; 1 bf16 silu; 2 bf16 gmul*acc; 3 fp32 acc*scale; 4 fp32 res+acc.
template <int BN, int EPI>
__global__ __launch_bounds__(512)
void gemm_pipe(const short* __restrict__ A, const short* __restrict__ B,
               float* __restrict__ Cf, short* __restrict__ Cb,
               const short* __restrict__ gmul, const float* __restrict__ res,
               int K, int lda, int ldb, int ldc, float scale) {
  constexpr int BM = 256;
  constexpr int LPS = (BN == 256) ? 4 : 3;   // global_load_lds per thread per stage
  constexpr int WR = (BN == 256) ? 2 : 4;    // wave grid WR x WC
  constexpr int WC = 8 / WR;
  constexpr int MF = BM / WR / 16;           // A fragments per wave (8 or 4)
  constexpr int NF = BN / WC / 16;           // B fragments per wave (4)
  __shared__ short lds[4][(BM + BN) * 32];

  const int t = threadIdx.x;
  const int lane = t & 63, wid = t >> 6;
  const int wr = wid / WC, wc = wid % WC;
  const int llo = lane & 15, lhi = lane >> 4;

  // XCD-aware block swizzle (nwg always divisible by 8 here)
  const int nwg = gridDim.x * gridDim.y;
  int bid = blockIdx.y * gridDim.x + blockIdx.x;
  bid = (bid & 7) * (nwg >> 3) + (bid >> 3);
  const long m0 = (long)(bid / gridDim.x) * BM;
  const long n0 = (long)(bid % gridDim.x) * BN;

  // staging source offsets (inverse-swizzled global; LDS dest stays linear)
  const int ca0 = t, ca1 = t + 512;
  auto src_off = [&](int c, long r0, long ld) {
    int sb = swz(c * 16);
    return (r0 + (sb >> 6)) * ld + ((sb & 63) >> 1);
  };
  const long as0 = src_off(ca0, m0, lda);
  const long as1 = src_off(ca1, m0, lda);
  const long bs0 = src_off(ca0, n0, ldb);
  const long bs1 = (BN == 256) ? src_off(ca1, n0, ldb) : 0;

  f32x4 acc[MF][NF];
  #pragma unroll
  for (int m = 0; m < MF; m++)
    #pragma unroll
    for (int n = 0; n < NF; n++) acc[m][n] = (f32x4)(0.f);

  // fragment read offsets (swizzled, loop-invariant), in shorts
  int aoff[MF], boff[NF];
  #pragma unroll
  for (int m = 0; m < MF; m++) {
    int b = (wr * (BM / WR) + m * 16 + llo) * 64 + lhi * 16;
    aoff[m] = swz(b) >> 1;
  }
  #pragma unroll
  for (int n = 0; n < NF; n++) {
    int b = (wc * (BN / WC) + n * 16 + llo) * 64 + lhi * 16;
    boff[n] = swz(b) >> 1;
  }

  auto stage = [&](int ks) {
    short* la = (short*)lds[ks & 3];
    short* lb = la + BM * 32;
    const long kk = (long)ks * 32;
    GLDS16(A + as0 + kk, la + ca0 * 8);
    GLDS16(A + as1 + kk, la + ca1 * 8);
    GLDS16(B + bs0 + kk, lb + ca0 * 8);
    if constexpr (BN == 256) GLDS16(B + bs1 + kk, lb + ca1 * 8);
  };

  auto phase_compute = [&](int ks) {
    const short* la = (const short*)lds[ks & 3];
    const short* lb = la + BM * 32;
    s16x8 af[MF], bf[NF];
    #pragma unroll
    for (int m = 0; m < MF; m++) af[m] = *(const s16x8*)(la + aoff[m]);
    #pragma unroll
    for (int n = 0; n < NF; n++) bf[n] = *(const s16x8*)(lb + boff[n]);
    __builtin_amdgcn_s_setprio(1);
    #pragma unroll
    for (int m = 0; m < MF; m++)
      #pragma unroll
      for (int n = 0; n < NF; n++)
        acc[m][n] = __builtin_amdgcn_mfma_f32_16x16x32_bf16(af[m], bf[n], acc[m][n], 0, 0, 0);
    __builtin_amdgcn_s_setprio(0);
  };

  const int NPH = K >> 5;   // K/32 >= 64 for all our shapes
  stage(0); stage(1); stage(2);
  waitvm<2 * LPS>();
  __builtin_amdgcn_s_barrier();
  for (int p = 0; p < NPH - 3; ++p) {
    stage(p + 3);                 // issue next tile first (hide HBM latency)
    phase_compute(p);
    waitvm<2 * LPS>();            // slot p+1 landed (counted, never 0)
    __builtin_amdgcn_s_barrier();
  }
  phase_compute(NPH - 3);
  waitvm<LPS>();
  __builtin_amdgcn_s_barrier();
  phase_compute(NPH - 2);
  waitvm<0>();
  __builtin_amdgcn_s_barrier();
  phase_compute(NPH - 1);

  // epilogue
  #pragma unroll
  for (int m = 0; m < MF; m++) {
    const long row0 = m0 + wr * (BM / WR) + m * 16 + lhi * 4;
    #pragma unroll
    for (int n = 0; n < NF; n++) {
      const long col = n0 + wc * (BN / WC) + n * 16 + llo;
      #pragma unroll
      for (int r = 0; r < 4; r++) {
        float v = acc[m][n][r];
        long idx = (row0 + r) * (long)ldc + col;
        if (EPI == 0) {
          Cb[idx] = f2bf(v);
        } else if (EPI == 1) {
          Cb[idx] = f2bf(v / (1.0f + __expf(-v)));
        } else if (EPI == 2) {
          Cb[idx] = f2bf(bf2f(gmul[idx]) * v);
        } else if (EPI == 3) {
          Cf[idx] = v * scale;
        } else {
          Cf[idx] = res[idx] + v;
        }
      }
    }
  }
}

extern "C" void kernel_launch(void* const* d_in, const int* in_sizes, int n_in,
                              void* d_out, int out_size, void* d_ws, size_t ws_size,
                              hipStream_t stream) {
  const float* x      = (const float*)d_in[0];
  const float* w_rn1  = (const float*)d_in[1];
  const float* wq     = (const float*)d_in[2];
  const float* wk     = (const float*)d_in[3];
  const float* wv     = (const float*)d_in[4];
  const float* wo     = (const float*)d_in[5];
  const float* w_rn2  = (const float*)d_in[6];
  const float* w_gate = (const float*)d_in[7];
  const float* w_up   = (const float*)d_in[8];
  const float* w_down = (const float*)d_in[9];
  const float* cosb   = (const float*)d_in[10];
  const float* sinb   = (const float*)d_in[11];
  float* out = (float*)d_out;

  const long S = S_LEN, D = D_MODEL, FF = FF_DIM;
  char* ws = (char*)d_ws;
  size_t off = 0;
  auto alloc = [&](size_t bytes) { void* p = ws + off; off += (bytes + 255) & ~(size_t)255; return p; };

  short* qkv  = (short*)alloc(S * QKV_LD * 2);  // [S][q|k|v], ao overwrites v-cols later
  short* vT   = (short*)alloc(D * S * 2);       // v transposed [D][S]
  short* hb   = (short*)alloc(S * D * 2);       // rmsnorm out (reused for rms2)
  float* x1   = (float*)alloc(S * D * 4);       // residual-1 (fp32)
  short* wbuf = (short*)alloc(FF * D * 2);      // converted weight slot (max size)
  char*  u2   = (char*)alloc(S * S * 4);        // scores fp32, later SwiGLU bf16 [S,FF]
  float* sraw = (float*)u2;
  short* gbuf = (short*)u2;
  short* pb   = (short*)alloc(S * S * 2);       // probabilities bf16

  const float inv_scale = 1.0f / sqrtf((float)D_MODEL);
  const long DD = D * D, FD = FF * D;
  const int convDD = (int)(DD / 8 / 256), convFD = (int)(FD / 8 / 256);
  dim3 blk(256), blk5(512);
  dim3 gQKV(3 * D_MODEL / 256, S_LEN / 256);    // 24 x 16 = 384
  dim3 gS(S_LEN / 256, S_LEN / 256);            // 16 x 16 = 256
  dim3 gN2048(D_MODEL / 128, S_LEN / 256);      // 16 x 16 = 256 (BN=128)
  dim3 gF(FF_DIM / 256, S_LEN / 256);           // 32 x 16 = 512

  // 1. rms1
  rmsnorm_kernel<<<S_LEN, 256, 0, stream>>>(x, w_rn1, hb);
  // 2. fused QKV projection: wbuf = [wq; wk; wv] bf16, one GEMM N=6144
  conv_f32_bf16<<<convDD, blk, 0, stream>>>(wq, wbuf, DD);
  conv_f32_bf16<<<convDD, blk, 0, stream>>>(wk, wbuf + DD, DD);
  conv_f32_bf16<<<convDD, blk, 0, stream>>>(wv, wbuf + 2 * DD, DD);
  gemm_pipe<256, 0><<<gQKV, blk5, 0, stream>>>(hb, wbuf, nullptr, qkv, nullptr, nullptr,
                                               D_MODEL, D_MODEL, D_MODEL, QKV_LD, 1.f);
  // 3. RoPE on q, k (in place, strided)
  rope_kernel<<<dim3(S_LEN, 2), blk, 0, stream>>>(qkv, cosb, sinb);
  // 4. v -> vT
  transpose_kernel<<<dim3(D_MODEL / 32, S_LEN / 32), dim3(32, 8), 0, stream>>>(
      qkv + 2 * D_MODEL, vT, S_LEN, D_MODEL, QKV_LD);
  // 5. scores = q k^T / sqrt(D)  (fp32)
  gemm_pipe<256, 3><<<gS, blk5, 0, stream>>>(qkv, qkv + D_MODEL, sraw, nullptr, nullptr, nullptr,
                                             D_MODEL, QKV_LD, QKV_LD, S_LEN, inv_scale);
  // 6. softmax -> pb (bf16)
  softmax_kernel<<<S_LEN, 256, 0, stream>>>(sraw, pb);
  // 7. attn out = P @ V  -> into dead v-columns of qkv
  gemm_pipe<128, 0><<<gN2048, blk5, 0, stream>>>(pb, vT, nullptr, qkv + 2 * D_MODEL, nullptr, nullptr,
                                                 S_LEN, S_LEN, S_LEN, QKV_LD, 1.f);
  // 8. x1 = x + ao @ wo^T
  conv_f32_bf16<<<convDD, blk, 0, stream>>>(wo, wbuf, DD);
  gemm_pipe<128, 4><<<gN2048, blk5, 0, stream>>>(qkv + 2 * D_MODEL, wbuf, x1, nullptr, nullptr, x,
                                                 D_MODEL, QKV_LD, D_MODEL, D_MODEL, 1.f);
  // 9. rms2
  rmsnorm_kernel<<<S_LEN, 256, 0, stream>>>(x1, w_rn2, hb);
  // 10. gate = silu(h @ wg^T)
  conv_f32_bf16<<<convFD, blk, 0, stream>>>(w_gate, wbuf, FD);
  gemm_pipe<256, 1><<<gF, blk5, 0, stream>>>(hb, wbuf, nullptr, gbuf, nullptr, nullptr,
                                             D_MODEL, D_MODEL, D_MODEL, FF_DIM, 1.f);
  // 11. g = gate * (h @ wu^T)   (in place on gbuf)
  conv_f32_bf16<<<convFD, blk, 0, stream>>>(w_up, wbuf, FD);
  gemm_pipe<256, 2><<<gF, blk5, 0, stream>>>(hb, wbuf, nullptr, gbuf, gbuf, nullptr,
                                             D_MODEL, D_MODEL, D_MODEL, FF_DIM, 1.f);
  // 12. out = x1 + g @ wd^T
  conv_f32_bf16<<<convFD, blk, 0, stream>>>(w_down, wbuf, FD);
  gemm_pipe<128, 4><<<gN2048, blk5, 0, stream>>>(gbuf, wbuf, out, nullptr, nullptr, x1,
                                                 FF_DIM, FF_DIM, FF_DIM, D_MODEL, 1.f);
}